// Round 1
// baseline (2738.520 us; speedup 1.0000x reference)
//
#include <hip/hip_runtime.h>
#include <math.h>

#define B_ 64
#define T_ 1024
#define D_ 256
#define U_ 256

// ---------------------------------------------------------------------------
// Kernel 1: proj = inputs @ W_xh + b_h, written into d_out (reused as xW buf).
// Classic fp32 tile GEMM: 64x64 tile, BK=16, 256 threads, 4x4 micro-tile.
// ---------------------------------------------------------------------------
#define BM 64
#define BN 64
#define BK 16

__global__ __launch_bounds__(256, 2)
void proj_gemm(const float* __restrict__ A,      // [M, D_] inputs
               const float* __restrict__ Bm,     // [D_, U_] W_xh
               const float* __restrict__ bias,   // [U_]
               float* __restrict__ C) {          // [M, U_] out
    __shared__ float As[BK][BM];   // transposed A tile: As[k][m]
    __shared__ float Bs[BK][BN];

    const int m0 = blockIdx.x * BM;
    const int n0 = blockIdx.y * BN;
    const int tid = (int)threadIdx.x;
    const int tx = tid & 15;        // output col group
    const int ty = tid >> 4;        // output row group

    // A-load mapping: thread -> (row, k-quad)
    const int ar  = tid >> 2;       // 0..63
    const int akq = tid & 3;        // 0..3 (float4 along k)
    // B-load mapping: thread -> (k, n-quad)
    const int bk  = tid >> 4;       // 0..15
    const int bnq = tid & 15;       // 0..15 (float4 along n)

    float acc[4][4] = {};

    for (int k0 = 0; k0 < D_; k0 += BK) {
        float4 av = *(const float4*)&A[(size_t)(m0 + ar) * D_ + k0 + akq * 4];
        float4 bv = *(const float4*)&Bm[(size_t)(k0 + bk) * U_ + n0 + bnq * 4];
        __syncthreads();            // previous chunk's reads done
        As[akq * 4 + 0][ar] = av.x;
        As[akq * 4 + 1][ar] = av.y;
        As[akq * 4 + 2][ar] = av.z;
        As[akq * 4 + 3][ar] = av.w;
        *(float4*)&Bs[bk][bnq * 4] = bv;
        __syncthreads();
        #pragma unroll
        for (int kk = 0; kk < BK; ++kk) {
            float4 a = *(const float4*)&As[kk][ty * 4];
            float4 b = *(const float4*)&Bs[kk][tx * 4];
            acc[0][0] = fmaf(a.x, b.x, acc[0][0]);
            acc[0][1] = fmaf(a.x, b.y, acc[0][1]);
            acc[0][2] = fmaf(a.x, b.z, acc[0][2]);
            acc[0][3] = fmaf(a.x, b.w, acc[0][3]);
            acc[1][0] = fmaf(a.y, b.x, acc[1][0]);
            acc[1][1] = fmaf(a.y, b.y, acc[1][1]);
            acc[1][2] = fmaf(a.y, b.z, acc[1][2]);
            acc[1][3] = fmaf(a.y, b.w, acc[1][3]);
            acc[2][0] = fmaf(a.z, b.x, acc[2][0]);
            acc[2][1] = fmaf(a.z, b.y, acc[2][1]);
            acc[2][2] = fmaf(a.z, b.z, acc[2][2]);
            acc[2][3] = fmaf(a.z, b.w, acc[2][3]);
            acc[3][0] = fmaf(a.w, b.x, acc[3][0]);
            acc[3][1] = fmaf(a.w, b.y, acc[3][1]);
            acc[3][2] = fmaf(a.w, b.z, acc[3][2]);
            acc[3][3] = fmaf(a.w, b.w, acc[3][3]);
        }
    }

    const float4 bb = *(const float4*)&bias[n0 + tx * 4];
    #pragma unroll
    for (int i = 0; i < 4; ++i) {
        const int row = m0 + ty * 4 + i;
        float4 o;
        o.x = acc[i][0] + bb.x;
        o.y = acc[i][1] + bb.y;
        o.z = acc[i][2] + bb.z;
        o.w = acc[i][3] + bb.w;
        *(float4*)&C[(size_t)row * U_ + n0 + tx * 4] = o;
    }
}

// ---------------------------------------------------------------------------
// Kernel 2: sequential recurrence, one block per batch element.
// Thread u holds W_hh[:,u] in 256 VGPRs; h double-buffered in LDS; xW is read
// from d_out (written by kernel 1) and overwritten in place with h_t.
// Thread u only ever touches column [b, :, u] of d_out -> race-free.
// ---------------------------------------------------------------------------
__global__ __launch_bounds__(256, 1)
void rnn_scan(const float* __restrict__ W_hh,   // [U_, U_]
              float* __restrict__ out) {        // [B_, T_, U_]: xW in, h out
    const int b = (int)blockIdx.x;
    const int u = (int)threadIdx.x;

    __shared__ float h[2][U_];

    // Load my column of W_hh into registers (coalesced across threads per k).
    float w[U_];
    #pragma unroll
    for (int k = 0; k < U_; ++k) w[k] = W_hh[(size_t)k * U_ + u];

    h[0][u] = 0.0f;
    __syncthreads();

    float* colp = out + (size_t)b * T_ * U_ + u;   // my private column
    float xw_next = colp[0];                        // prefetch t=0
    int cur = 0;

    for (int t = 0; t < T_; ++t) {
        float acc = xw_next;
        if (t + 1 < T_) xw_next = colp[(size_t)(t + 1) * U_];  // prefetch ahead

        const float4* h4 = (const float4*)h[cur];
        #pragma unroll
        for (int kk = 0; kk < U_ / 4; ++kk) {
            float4 hv = h4[kk];                    // broadcast ds_read_b128
            acc = fmaf(hv.x, w[4 * kk + 0], acc);
            acc = fmaf(hv.y, w[4 * kk + 1], acc);
            acc = fmaf(hv.z, w[4 * kk + 2], acc);
            acc = fmaf(hv.w, w[4 * kk + 3], acc);
        }

        const float hn = tanhf(acc);
        colp[(size_t)t * U_] = hn;                 // overwrite xW with h_t
        h[1 - cur][u] = hn;
        cur ^= 1;
        __syncthreads();                           // one barrier per step
    }
}

// ---------------------------------------------------------------------------
extern "C" void kernel_launch(void* const* d_in, const int* in_sizes, int n_in,
                              void* d_out, int out_size, void* d_ws, size_t ws_size,
                              hipStream_t stream) {
    const float* inputs = (const float*)d_in[0];   // [B, T, D]
    const float* W_xh   = (const float*)d_in[1];   // [D, U]
    const float* W_hh   = (const float*)d_in[2];   // [U, U]
    const float* b_h    = (const float*)d_in[3];   // [U]
    float* out = (float*)d_out;                    // [B, T, U]

    const int M = B_ * T_;                         // 65536
    dim3 g1(M / BM, U_ / BN);                      // (1024, 4)
    proj_gemm<<<g1, 256, 0, stream>>>(inputs, W_xh, b_h, out);
    rnn_scan<<<B_, U_, 0, stream>>>(W_hh, out);
}

// Round 2
// 915.341 us; speedup vs baseline: 2.9918x; 2.9918x over previous
//
#include <hip/hip_runtime.h>
#include <math.h>

#define B_ 64
#define T_ 1024
#define D_ 256
#define U_ 256

// ---------------------------------------------------------------------------
// Kernel 1: proj = inputs @ W_xh + b_h, written into d_out (reused as xW buf).
// Classic fp32 tile GEMM: 64x64 tile, BK=16, 256 threads, 4x4 micro-tile.
// ---------------------------------------------------------------------------
#define BM 64
#define BN 64
#define BK 16

__global__ __launch_bounds__(256, 2)
void proj_gemm(const float* __restrict__ A,      // [M, D_] inputs
               const float* __restrict__ Bm,     // [D_, U_] W_xh
               const float* __restrict__ bias,   // [U_]
               float* __restrict__ C) {          // [M, U_] out
    __shared__ float As[BK][BM];   // transposed A tile: As[k][m]
    __shared__ float Bs[BK][BN];

    const int m0 = blockIdx.x * BM;
    const int n0 = blockIdx.y * BN;
    const int tid = (int)threadIdx.x;
    const int tx = tid & 15;        // output col group
    const int ty = tid >> 4;        // output row group

    const int ar  = tid >> 2;       // 0..63
    const int akq = tid & 3;        // 0..3 (float4 along k)
    const int bk  = tid >> 4;       // 0..15
    const int bnq = tid & 15;       // 0..15 (float4 along n)

    float acc[4][4] = {};

    for (int k0 = 0; k0 < D_; k0 += BK) {
        float4 av = *(const float4*)&A[(size_t)(m0 + ar) * D_ + k0 + akq * 4];
        float4 bv = *(const float4*)&Bm[(size_t)(k0 + bk) * U_ + n0 + bnq * 4];
        __syncthreads();
        As[akq * 4 + 0][ar] = av.x;
        As[akq * 4 + 1][ar] = av.y;
        As[akq * 4 + 2][ar] = av.z;
        As[akq * 4 + 3][ar] = av.w;
        *(float4*)&Bs[bk][bnq * 4] = bv;
        __syncthreads();
        #pragma unroll
        for (int kk = 0; kk < BK; ++kk) {
            float4 a = *(const float4*)&As[kk][ty * 4];
            float4 b = *(const float4*)&Bs[kk][tx * 4];
            acc[0][0] = fmaf(a.x, b.x, acc[0][0]);
            acc[0][1] = fmaf(a.x, b.y, acc[0][1]);
            acc[0][2] = fmaf(a.x, b.z, acc[0][2]);
            acc[0][3] = fmaf(a.x, b.w, acc[0][3]);
            acc[1][0] = fmaf(a.y, b.x, acc[1][0]);
            acc[1][1] = fmaf(a.y, b.y, acc[1][1]);
            acc[1][2] = fmaf(a.y, b.z, acc[1][2]);
            acc[1][3] = fmaf(a.y, b.w, acc[1][3]);
            acc[2][0] = fmaf(a.z, b.x, acc[2][0]);
            acc[2][1] = fmaf(a.z, b.y, acc[2][1]);
            acc[2][2] = fmaf(a.z, b.z, acc[2][2]);
            acc[2][3] = fmaf(a.z, b.w, acc[2][3]);
            acc[3][0] = fmaf(a.w, b.x, acc[3][0]);
            acc[3][1] = fmaf(a.w, b.y, acc[3][1]);
            acc[3][2] = fmaf(a.w, b.z, acc[3][2]);
            acc[3][3] = fmaf(a.w, b.w, acc[3][3]);
        }
    }

    const float4 bb = *(const float4*)&bias[n0 + tx * 4];
    #pragma unroll
    for (int i = 0; i < 4; ++i) {
        const int row = m0 + ty * 4 + i;
        float4 o;
        o.x = acc[i][0] + bb.x;
        o.y = acc[i][1] + bb.y;
        o.z = acc[i][2] + bb.z;
        o.w = acc[i][3] + bb.w;
        *(float4*)&C[(size_t)row * U_ + n0 + tx * 4] = o;
    }
}

// ---------------------------------------------------------------------------
// Kernel 2: sequential recurrence, one block per batch element.
// 512 threads = 8 waves (2/SIMD). Wave g owns k-range [g*32, g*32+32);
// lane l owns u-columns [4l, 4l+4). Per-thread W_hh slice: 32 x float4
// = 128 VGPRs (under the 256 arch-VGPR encoding limit -> no spill, unlike
// the 256-float/thread version which the compiler refused to registerize).
// h is double-buffered in LDS; k-group partials reduced via an 8x256 LDS
// buffer by 4 finalize waves (1/SIMD). xW read from d_out (written by
// kernel 1), prefetched 2 steps ahead; h_t overwrites xW in place
// (thread-private column per finalize thread -> race-free).
// ---------------------------------------------------------------------------
#define NT_  512
#define KG_  8
#define KPT_ 32

__global__ __launch_bounds__(NT_, 2)
void rnn_scan(const float* __restrict__ W_hh,   // [U_, U_]
              float* __restrict__ out) {        // [B_, T_, U_]: xW in, h out
    const int b    = (int)blockIdx.x;
    const int tid  = (int)threadIdx.x;
    const int kg   = tid >> 6;        // 0..7, wave-uniform k-group
    const int lane = tid & 63;
    const int u0   = lane * 4;        // u base (4 columns per thread)
    const int k0   = kg * KPT_;       // k base (32 rows per thread)

    __shared__ float h[2][U_];        // double-buffered hidden state
    __shared__ float part[KG_][U_];   // per-k-group partial sums

    // W_hh slice into registers: w4[k] = W_hh[k0+k][u0..u0+3], coalesced.
    float4 w4[KPT_];
    #pragma unroll
    for (int k = 0; k < KPT_; ++k)
        w4[k] = *(const float4*)&W_hh[(size_t)(k0 + k) * U_ + u0];

    if (tid < U_) h[0][tid] = 0.0f;   // h[1] is written before first read

    // Finalize threads (tid < 256, u = tid) own column [b, :, u] of out.
    float* colp = out + (size_t)b * T_ * U_ + tid;
    float xw0 = 0.0f, xw1 = 0.0f;
    if (tid < U_) {
        xw0 = colp[0];                 // t = 0
        xw1 = colp[U_];                // t = 1
    }
    __syncthreads();

    int cur = 0;
    for (int t = 0; t < T_; ++t) {
        // ---- partial matvec: acc[j] = sum_{k in group} h[k] * W[k][u0+j]
        float4 acc = make_float4(0.f, 0.f, 0.f, 0.f);
        const float4* h4 = (const float4*)&h[cur][k0];  // wave-uniform addr
        #pragma unroll
        for (int kk = 0; kk < KPT_ / 4; ++kk) {
            const float4 hv = h4[kk];                    // LDS broadcast read
            const float4 wa = w4[4 * kk + 0];
            const float4 wb = w4[4 * kk + 1];
            const float4 wc = w4[4 * kk + 2];
            const float4 wd = w4[4 * kk + 3];
            acc.x = fmaf(hv.x, wa.x, acc.x);
            acc.y = fmaf(hv.x, wa.y, acc.y);
            acc.z = fmaf(hv.x, wa.z, acc.z);
            acc.w = fmaf(hv.x, wa.w, acc.w);
            acc.x = fmaf(hv.y, wb.x, acc.x);
            acc.y = fmaf(hv.y, wb.y, acc.y);
            acc.z = fmaf(hv.y, wb.z, acc.z);
            acc.w = fmaf(hv.y, wb.w, acc.w);
            acc.x = fmaf(hv.z, wc.x, acc.x);
            acc.y = fmaf(hv.z, wc.y, acc.y);
            acc.z = fmaf(hv.z, wc.z, acc.z);
            acc.w = fmaf(hv.z, wc.w, acc.w);
            acc.x = fmaf(hv.w, wd.x, acc.x);
            acc.y = fmaf(hv.w, wd.y, acc.y);
            acc.z = fmaf(hv.w, wd.z, acc.z);
            acc.w = fmaf(hv.w, wd.w, acc.w);
        }
        *(float4*)&part[kg][u0] = acc;   // conflict-free b128 write
        __syncthreads();

        // ---- finalize: 4 waves (tid < 256), u = tid
        if (tid < U_) {
            float s = xw0;
            #pragma unroll
            for (int g = 0; g < KG_; ++g)
                s += part[g][tid];       // stride-1 across lanes: no conflict
            // rotate the xW prefetch pipeline (distance 2 covers HBM miss)
            xw0 = xw1;
            if (t + 2 < T_) xw1 = colp[(size_t)(t + 2) * U_];
            const float hn = tanhf(s);
            h[1 - cur][tid] = hn;
            colp[(size_t)t * U_] = hn;   // overwrite xW with h_t
        }
        cur ^= 1;
        __syncthreads();
    }
}

// ---------------------------------------------------------------------------
extern "C" void kernel_launch(void* const* d_in, const int* in_sizes, int n_in,
                              void* d_out, int out_size, void* d_ws, size_t ws_size,
                              hipStream_t stream) {
    const float* inputs = (const float*)d_in[0];   // [B, T, D]
    const float* W_xh   = (const float*)d_in[1];   // [D, U]
    const float* W_hh   = (const float*)d_in[2];   // [U, U]
    const float* b_h    = (const float*)d_in[3];   // [U]
    float* out = (float*)d_out;                    // [B, T, U]

    const int M = B_ * T_;                         // 65536
    dim3 g1(M / BM, U_ / BN);                      // (1024, 4)
    proj_gemm<<<g1, 256, 0, stream>>>(inputs, W_xh, b_h, out);
    rnn_scan<<<B_, NT_, 0, stream>>>(W_hh, out);
}